// Round 6
// baseline (1097.061 us; speedup 1.0000x reference)
//
#include <hip/hip_runtime.h>
#include <hip/hip_bf16.h>

// MixSoftmax: B=4 S=1024 H=1024 K=8 E=512 C=10000
// out[t,c] = sum_k softmax_k(ctx@prior_w^T)[t,k] * softmax_c(tanh(ctx@latent_w^T)[t,k,:] @ dec_w^T)[c]
//
// R3: m97-style global_load_lds mainloop (16B DMA, linear LDS, 2 barriers/K).
// R4: XOR-swizzle (rule #21) -> bank conflicts 1.24e8 -> 0, MfmaUtil 26->35%.
// R6: chunked P-store path: pass1<1> stores P=fp16(exp(logit+bias)), Z from
// ROUNDED values; streaming combine replaces the duplicate decoder GEMM.
// R7: cap chunk at 4096 rows -> P chunk = 82.8 MB, L3-resident. The
// pass1->combine P round-trip stays in Infinity Cache instead of costing
// ~1.3 GB of HBM traffic (R4 counters: WRITE_SIZE 667 MB on pass1).
// R8 (this round): resubmit of R7 — previous bench died with an MI355X
// container infra error (host-side-only change, no kernel-defect mechanism).

#define BM 128
#define BN 128
#define BK 64

typedef __attribute__((ext_vector_type(8))) short bf16x8;
typedef __attribute__((ext_vector_type(4))) float f32x4;
typedef __attribute__((ext_vector_type(8))) _Float16 f16x8;

typedef const __attribute__((address_space(1))) unsigned int* gas_u32p;
typedef __attribute__((address_space(3))) unsigned int* las_u32p;

__device__ __forceinline__ unsigned short f2bf(float x) {
  union { float f; unsigned int u; } un; un.f = x;
  unsigned int r = un.u + 0x7FFFu + ((un.u >> 16) & 1u);
  return (unsigned short)(r >> 16);
}

__global__ void k_cvt_bf16(const float4* __restrict__ src, ushort4* __restrict__ dst, int n4) {
  int i = blockIdx.x * blockDim.x + threadIdx.x;
  if (i < n4) {
    float4 v = src[i];
    ushort4 o;
    o.x = f2bf(v.x); o.y = f2bf(v.y); o.z = f2bf(v.z); o.w = f2bf(v.w);
    dst[i] = o;
  }
}

__global__ void k_priors(const float* __restrict__ ctx, const float* __restrict__ pw,
                         const float* __restrict__ pb, float* __restrict__ priors) {
  int t = blockIdx.x;
  int lane = threadIdx.x;  // 64 threads
  __shared__ float logit[8];
  const float* c = ctx + (size_t)t * 1024;
  for (int k = 0; k < 8; ++k) {
    const float* w = pw + k * 1024;
    float s = 0.f;
    for (int h = lane; h < 1024; h += 64) s += c[h] * w[h];
    #pragma unroll
    for (int m = 1; m <= 32; m <<= 1) s += __shfl_xor(s, m);
    if (lane == 0) logit[k] = s + pb[k];
  }
  __syncthreads();
  if (lane == 0) {
    float mx = logit[0];
    for (int k = 1; k < 8; ++k) mx = fmaxf(mx, logit[k]);
    float z = 0.f, e[8];
    for (int k = 0; k < 8; ++k) { e[k] = __expf(logit[k] - mx); z += e[k]; }
    float inv = 1.f / z;
    for (int k = 0; k < 8; ++k) priors[(size_t)t * 8 + k] = e[k] * inv;
  }
}

// Shared GEMM mainloop: C[m,n] = A[m,:] . B[n,:]  (both row-major, K contiguous)
// 128x128 tile, 4 waves in 2x2, each wave 64x64 = 4x4 frags of 16x16, BK=64.
// Per K-step: { barrier; 8x global_load_lds(16B, source pre-swizzled);
// barrier (vmcnt0 drain); swizzled ds_read_b128 frags + 32 MFMA }.
// Swizzle: 16B-chunk kc of row r lives at LDS chunk slot kc^(r&7).
__device__ __forceinline__ void gemm_mainloop(
    const unsigned short* __restrict__ A, const unsigned short* __restrict__ B,
    int lda, int ldb, int m0, int n0, int ktiles,
    unsigned short* ldsA, unsigned short* ldsB, f32x4 acc[4][4]) {
  const int tid = threadIdx.x;
  const int lane = tid & 63;
  const int wave = tid >> 6;
  const int wm = wave & 1, wn = wave >> 1;
  const int lrow = lane & 15, lq = lane >> 4;

  for (int kt = 0; kt < ktiles; ++kt) {
    int k0 = kt * BK;
    __syncthreads();   // previous iter's LDS reads complete before DMA overwrites
    #pragma unroll
    for (int p = 0; p < 4; ++p) {
      int chunk = p * 256 + tid;          // 0..1023, 16B each = full 16KB tile
      int row = chunk >> 3, kc = chunk & 7;
      int kcs = kc ^ (row & 7);           // inverse-swizzle the global source
      __builtin_amdgcn_global_load_lds(
          (gas_u32p)(A + (size_t)(m0 + row) * lda + k0 + kcs * 8),
          (las_u32p)(ldsA + chunk * 8), 16, 0, 0);
      __builtin_amdgcn_global_load_lds(
          (gas_u32p)(B + (size_t)(n0 + row) * ldb + k0 + kcs * 8),
          (las_u32p)(ldsB + chunk * 8), 16, 0, 0);
    }
    __syncthreads();   // compiler emits vmcnt(0) drain: staged tiles visible
    #pragma unroll
    for (int s = 0; s < 2; ++s) {
      // swizzled read column: chunk (s*4+lq) of row (..+lrow) sits at slot ^(lrow&7)
      int cbyteoff = (((s * 4 + lq) ^ (lrow & 7)) * 8);
      bf16x8 af[4], bfr[4];
      #pragma unroll
      for (int f = 0; f < 4; ++f)
        af[f] = *(const bf16x8*)(ldsA + (wm * 64 + f * 16 + lrow) * BK + cbyteoff);
      #pragma unroll
      for (int f = 0; f < 4; ++f)
        bfr[f] = *(const bf16x8*)(ldsB + (wn * 64 + f * 16 + lrow) * BK + cbyteoff);
      #pragma unroll
      for (int fi = 0; fi < 4; ++fi)
        #pragma unroll
        for (int fj = 0; fj < 4; ++fj)
          acc[fi][fj] = __builtin_amdgcn_mfma_f32_16x16x32_bf16(af[fi], bfr[fj], acc[fi][fj], 0, 0, 0);
    }
  }
}

// Latent: [4096x1024] @ [4096x1024]^T, epilogue tanh(+bias), store bf16
// 1024 blocks: xcd-sliced (8 xcd x 4 col-tiles x 32 row-tiles)
__global__ __launch_bounds__(256, 4)
void k_latent(const unsigned short* __restrict__ ctxb, const unsigned short* __restrict__ lwb,
              const float* __restrict__ lb, unsigned short* __restrict__ latent) {
  __shared__ unsigned short lds[(BM + BN) * BK];
  f32x4 zero = {0.f, 0.f, 0.f, 0.f};
  f32x4 acc[4][4];
  #pragma unroll
  for (int i = 0; i < 4; ++i)
    #pragma unroll
    for (int j = 0; j < 4; ++j) acc[i][j] = zero;
  int l = blockIdx.x;
  int xcd = l & 7, idx = l >> 3;
  int ctl = idx & 3, by = idx >> 2;
  int m0 = by * BM, n0 = (xcd * 4 + ctl) * BN;
  gemm_mainloop(ctxb, lwb, 1024, 1024, m0, n0, 1024 / BK, lds, lds + BM * BK, acc);

  const int lane = threadIdx.x & 63, wave = threadIdx.x >> 6;
  const int wm = wave & 1, wn = wave >> 1, lrow = lane & 15, lq = lane >> 4;
  #pragma unroll
  for (int fi = 0; fi < 4; ++fi)
    #pragma unroll
    for (int fj = 0; fj < 4; ++fj) {
      int gcol = n0 + wn * 64 + fj * 16 + lrow;
      float bias = lb[gcol];
      #pragma unroll
      for (int r = 0; r < 4; ++r) {
        int grow = m0 + wm * 64 + fi * 16 + lq * 4 + r;
        float v = tanhf(acc[fi][fj][r] + bias);
        latent[(size_t)grow * 4096 + gcol] = f2bf(v);
      }
    }
}

// Decoder pass 1 over a row-chunk [m_base, m_base+rows): logits tile -> exp ->
// per-row sums -> atomicAdd Z.
// STORE=1: round exp to fp16, accumulate Z from the ROUNDED values, stage the
// 128x128 fp16 tile in LDS (16B-chunk XOR swizzle), write P (chunk-local rows)
// coalesced 16B/lane.
// grid: (rows/128)*80; xcd = l&7 owns col-tiles [xcd*10, xcd*10+10)
template<int STORE>
__global__ __launch_bounds__(256, 4)
void k_dec_pass1(const unsigned short* __restrict__ latb, const unsigned short* __restrict__ dwb,
                 const float* __restrict__ db, float* __restrict__ Z,
                 _Float16* __restrict__ P, int m_base) {
  __shared__ unsigned short lds[(BM + BN) * BK];
  int l = blockIdx.x;
  int xcd = l & 7, idx = l >> 3;
  int ctl = idx % 10, by = idx / 10;
  int n0 = (xcd * 10 + ctl) * BN, m0 = m_base + by * BM;
  if (n0 >= 10000) return;   // whole-block early exit (pure-pad tile), before any barrier

  f32x4 zero = {0.f, 0.f, 0.f, 0.f};
  f32x4 acc[4][4];
  #pragma unroll
  for (int i = 0; i < 4; ++i)
    #pragma unroll
    for (int j = 0; j < 4; ++j) acc[i][j] = zero;
  gemm_mainloop(latb, dwb, 512, 512, m0, n0, 512 / BK, lds, lds + BM * BK, acc);

  const int lane = threadIdx.x & 63, wave = threadIdx.x >> 6;
  const int wm = wave & 1, wn = wave >> 1, lrow = lane & 15, lq = lane >> 4;

  if (STORE) __syncthreads();       // mainloop LDS reads done in all waves before reuse
  _Float16* ldsP = (_Float16*)lds;  // 128x128 fp16 = 32 KB, exactly the LDS block

  float rowsum[4][4];
  #pragma unroll
  for (int fi = 0; fi < 4; ++fi)
    #pragma unroll
    for (int r = 0; r < 4; ++r) rowsum[fi][r] = 0.f;
  #pragma unroll
  for (int fj = 0; fj < 4; ++fj) {
    int gcol = n0 + wn * 64 + fj * 16 + lrow;
    bool valid = gcol < 10000;
    float bias = valid ? db[gcol] : 0.f;
    #pragma unroll
    for (int fi = 0; fi < 4; ++fi)
      #pragma unroll
      for (int r = 0; r < 4; ++r) {
        float e = __expf(acc[fi][fj][r] + bias);
        if (STORE) {
          _Float16 h = (_Float16)e;
          if (valid) rowsum[fi][r] += (float)h;
          int row_l = wm * 64 + fi * 16 + lq * 4 + r;
          int col_l = wn * 64 + fj * 16 + lrow;
          // 16B-chunk XOR swizzle: chunk (col>>3) of row r at slot ^(r&7)
          ldsP[row_l * 128 + (((col_l >> 3) ^ (row_l & 7)) << 3) + (col_l & 7)] = h;
        } else {
          if (valid) rowsum[fi][r] += e;
        }
      }
  }

  if (STORE) {
    __syncthreads();
    #pragma unroll
    for (int it = 0; it < 8; ++it) {
      int chunk = it * 256 + threadIdx.x;   // 0..2047 16B chunks = 32 KB
      int row_l = chunk >> 4, c8 = chunk & 15;
      int slot = c8 ^ (row_l & 7);
      uint4 v = *(const uint4*)((const char*)lds + row_l * 256 + slot * 16);
      // chunk-local row index: by*BM + row_l
      *(uint4*)(P + (size_t)(by * BM + row_l) * 10112 + n0 + c8 * 8) = v;
    }
  }

  #pragma unroll
  for (int fi = 0; fi < 4; ++fi)
    #pragma unroll
    for (int r = 0; r < 4; ++r) {
      float s = rowsum[fi][r];
      s += __shfl_xor(s, 1); s += __shfl_xor(s, 2);
      s += __shfl_xor(s, 4); s += __shfl_xor(s, 8);
      if (lrow == 0) atomicAdd(&Z[m0 + wm * 64 + fi * 16 + lq * 4 + r], s);
    }
}

// Combine (store path): out[t,c] = sum_k (prior/Z)[t,k] * P[tl*8+k][c].
// Pure streaming, 16B/lane fp16x8 loads, float4 stores. P chunk is
// L3-resident (R7) so the reads are Infinity-Cache hits.
// grid: (tokens_in_chunk, 5); block handles 256 col-chunks of 8.
__global__ __launch_bounds__(256)
void k_combine(const _Float16* __restrict__ P, const float* __restrict__ priors,
               const float* __restrict__ Z, float* __restrict__ out, int t_base) {
  int tl = blockIdx.x;              // chunk-local token
  int t  = t_base + tl;             // absolute token
  const _Float16* base = P + (size_t)tl * 8 * 10112;
  float w[8];
  #pragma unroll
  for (int k = 0; k < 8; ++k) w[k] = priors[t * 8 + k] / Z[t * 8 + k];
  int c8 = blockIdx.y * 256 + threadIdx.x;
  if (c8 < 1250) {
    int c = c8 * 8;
    float s[8] = {0.f, 0.f, 0.f, 0.f, 0.f, 0.f, 0.f, 0.f};
    #pragma unroll
    for (int k = 0; k < 8; ++k) {
      f16x8 v = *(const f16x8*)(base + (size_t)k * 10112 + c);
      #pragma unroll
      for (int j = 0; j < 8; ++j) s[j] += w[k] * (float)v[j];
    }
    float4 o0 = {s[0], s[1], s[2], s[3]};
    float4 o1 = {s[4], s[5], s[6], s[7]};
    *(float4*)(out + (size_t)t * 10000 + c) = o0;
    *(float4*)(out + (size_t)t * 10000 + c + 4) = o1;
  }
}

// Decoder pass 2 (fallback path, ws too small): recompute logits ->
// (prior/Z)*exp -> sum 8 k-rows -> stage 16x128 token tile -> float4 stores.
__global__ __launch_bounds__(256, 4)
void k_dec_pass2(const unsigned short* __restrict__ latb, const unsigned short* __restrict__ dwb,
                 const float* __restrict__ db, const float* __restrict__ priors,
                 const float* __restrict__ Z, float* __restrict__ out) {
  __shared__ unsigned short lds[(BM + BN) * BK];
  int l = blockIdx.x;
  int xcd = l & 7, idx = l >> 3;
  int ctl = idx % 10, by = idx / 10;
  int n0 = (xcd * 10 + ctl) * BN, m0 = by * BM;
  if (n0 >= 10000) return;

  f32x4 zero = {0.f, 0.f, 0.f, 0.f};
  f32x4 acc[4][4];
  #pragma unroll
  for (int i = 0; i < 4; ++i)
    #pragma unroll
    for (int j = 0; j < 4; ++j) acc[i][j] = zero;
  gemm_mainloop(latb, dwb, 512, 512, m0, n0, 512 / BK, lds, lds + BM * BK, acc);

  const int tid = threadIdx.x;
  const int lane = tid & 63, wave = tid >> 6;
  const int wm = wave & 1, wn = wave >> 1, lrow = lane & 15, lq = lane >> 4;

  __syncthreads();                    // mainloop LDS reads done in all waves
  float* ldsO = (float*)lds;          // reuse: 16 tokens x 128 cols = 8 KB

  #pragma unroll
  for (int fi = 0; fi < 4; ++fi) {
    int rbase = m0 + wm * 64 + fi * 16 + lq * 4;
    float w[4];
    #pragma unroll
    for (int r = 0; r < 4; ++r) w[r] = priors[rbase + r] / Z[rbase + r];
    #pragma unroll
    for (int fj = 0; fj < 4; ++fj) {
      int gcol = n0 + wn * 64 + fj * 16 + lrow;
      float bias = (gcol < 10000) ? db[gcol] : 0.f;
      float part = 0.f;
      #pragma unroll
      for (int r = 0; r < 4; ++r) part += w[r] * __expf(acc[fi][fj][r] + bias);
      // rows rbase..rbase+3 are k=0..3 of token (rbase>>3); k=4..7 at lane^16
      float tok = part + __shfl_xor(part, 16);
      if (!(lq & 1)) {
        int tl = wm * 8 + fi * 2 + (lq >> 1);     // local token 0..15
        int cl = wn * 64 + fj * 16 + lrow;        // local col 0..127
        ldsO[tl * 128 + cl] = tok;
      }
    }
  }
  __syncthreads();
  int tok0 = m0 >> 3;
  #pragma unroll
  for (int it = 0; it < 2; ++it) {
    int f = it * 256 + tid;           // 0..511 float4 slots
    int tl = f >> 5, c4 = f & 31;
    int col = n0 + c4 * 4;
    if (col < 10000)
      *(float4*)(out + (size_t)(tok0 + tl) * 10000 + col) = *(float4*)(ldsO + tl * 128 + c4 * 4);
  }
}

extern "C" void kernel_launch(void* const* d_in, const int* in_sizes, int n_in,
                              void* d_out, int out_size, void* d_ws, size_t ws_size,
                              hipStream_t stream) {
  const float* ctx = (const float*)d_in[0];  // [4096,1024]
  const float* pw  = (const float*)d_in[1];  // [8,1024]
  const float* pb  = (const float*)d_in[2];  // [8]
  const float* lw  = (const float*)d_in[3];  // [4096,1024]
  const float* lb  = (const float*)d_in[4];  // [4096]
  const float* dw  = (const float*)d_in[5];  // [10000,512]
  const float* db  = (const float*)d_in[6];  // [10000]
  float* out = (float*)d_out;

  char* ws = (char*)d_ws;
  unsigned short* ctxb = (unsigned short*)ws;                // 8,388,608 B
  unsigned short* lwb  = (unsigned short*)(ws + 8388608);    // 8,388,608 B
  unsigned short* dwb  = (unsigned short*)(ws + 16777216);   // 10112*512*2 = 10,354,688 B
  unsigned short* latb = (unsigned short*)(ws + 27131904);   // 32768*512*2 = 33,554,432 B
  float* priors        = (float*)(ws + 60686336);            // 131,072 B
  float* Z             = (float*)(ws + 60817408);            // 131,072 B
  _Float16* Pex        = (_Float16*)(ws + 60948480);         // chunk buffer, sized from ws
  const size_t WS_BASE = 60948480ull;

  // Chunk sizing: target 4096 rows -> P chunk = 4096*10112*2 = 82.8 MB,
  // L3-resident (chunk working set ~146 MB < 256 MB Infinity Cache), so the
  // pass1 P-writes and combine P-reads stay in L3 instead of HBM.
  size_t avail = ws_size > WS_BASE ? ws_size - WS_BASE : 0;
  long long mrows_ll = (long long)(avail / (10112ull * 2ull)) & ~127ll;
  if (mrows_ll > 4096) mrows_ll = 4096;
  int mrows = (int)mrows_ll;
  int nch = mrows > 0 ? (32768 + mrows - 1) / mrows : 1000;
  const bool store_path = (nch <= 16);

  k_cvt_bf16<<<4096, 256, 0, stream>>>((const float4*)ctx, (ushort4*)ctxb, 1048576);
  k_cvt_bf16<<<4096, 256, 0, stream>>>((const float4*)lw,  (ushort4*)lwb,  1048576);
  k_cvt_bf16<<<5000, 256, 0, stream>>>((const float4*)dw,  (ushort4*)dwb,  1280000);
  hipMemsetAsync(dwb + (size_t)10000 * 512, 0, (size_t)112 * 512 * 2, stream);  // zero pad rows
  hipMemsetAsync(Z, 0, 32768 * 4, stream);

  k_priors<<<4096, 64, 0, stream>>>(ctx, pw, pb, priors);
  k_latent<<<1024, 256, 0, stream>>>(ctxb, lwb, lb, latb);
  if (store_path) {
    for (int ms = 0; ms < 32768; ms += mrows) {
      int rows = 32768 - ms < mrows ? 32768 - ms : mrows;   // multiple of 128
      k_dec_pass1<1><<<(rows / 128) * 80, 256, 0, stream>>>(latb, dwb, db, Z, Pex, ms);
      k_combine<<<dim3(rows / 8, 5), 256, 0, stream>>>(Pex, priors, Z, out, ms / 8);
    }
  } else {
    k_dec_pass1<0><<<20480, 256, 0, stream>>>(latb, dwb, db, Z, nullptr, 0);
    k_dec_pass2<<<20480, 256, 0, stream>>>(latb, dwb, db, priors, Z, out);
  }
}

// Round 7
// 1002.861 us; speedup vs baseline: 1.0939x; 1.0939x over previous
//
#include <hip/hip_runtime.h>
#include <hip/hip_bf16.h>

// MixSoftmax: B=4 S=1024 H=1024 K=8 E=512 C=10000
// out[t,c] = sum_k softmax_k(ctx@prior_w^T)[t,k] * softmax_c(tanh(ctx@latent_w^T)[t,k,:] @ dec_w^T)[c]
//
// R3: m97-style global_load_lds mainloop (16B DMA, linear LDS, 2 barriers/K).
// R4: XOR-swizzle (rule #21) -> bank conflicts 1.24e8 -> 0, MfmaUtil 26->35%.
// R6: chunked P-store path: pass1<1> stores P=fp16(exp(logit+bias)), Z from
// ROUNDED values; streaming combine replaces the duplicate decoder GEMM.
// R7/R8: 4096-row chunks. MEASURED: combine-from-L3 confirmed (410->110 us),
// but pass1 per-chunk regressed 1.8x (2560-block grid = 2.5 resident-rounds,
// tail + ramp; Occ 44->34%, MfmaUtil 28->15%). L3 write-absorption refuted
// (WRITE_SIZE = full P chunk regardless).
// R9 (this round): mrows 4096 -> 8192. P chunk 165.7 MB (still L3-resident for
// combine reads; working set ~226 MB < 256 MB), pass1 grid 5120 blocks = 5.0
// resident-rounds -> tail fraction ~1/4 of R6's, 4 dispatch pairs not 8.

#define BM 128
#define BN 128
#define BK 64

typedef __attribute__((ext_vector_type(8))) short bf16x8;
typedef __attribute__((ext_vector_type(4))) float f32x4;
typedef __attribute__((ext_vector_type(8))) _Float16 f16x8;

typedef const __attribute__((address_space(1))) unsigned int* gas_u32p;
typedef __attribute__((address_space(3))) unsigned int* las_u32p;

__device__ __forceinline__ unsigned short f2bf(float x) {
  union { float f; unsigned int u; } un; un.f = x;
  unsigned int r = un.u + 0x7FFFu + ((un.u >> 16) & 1u);
  return (unsigned short)(r >> 16);
}

__global__ void k_cvt_bf16(const float4* __restrict__ src, ushort4* __restrict__ dst, int n4) {
  int i = blockIdx.x * blockDim.x + threadIdx.x;
  if (i < n4) {
    float4 v = src[i];
    ushort4 o;
    o.x = f2bf(v.x); o.y = f2bf(v.y); o.z = f2bf(v.z); o.w = f2bf(v.w);
    dst[i] = o;
  }
}

__global__ void k_priors(const float* __restrict__ ctx, const float* __restrict__ pw,
                         const float* __restrict__ pb, float* __restrict__ priors) {
  int t = blockIdx.x;
  int lane = threadIdx.x;  // 64 threads
  __shared__ float logit[8];
  const float* c = ctx + (size_t)t * 1024;
  for (int k = 0; k < 8; ++k) {
    const float* w = pw + k * 1024;
    float s = 0.f;
    for (int h = lane; h < 1024; h += 64) s += c[h] * w[h];
    #pragma unroll
    for (int m = 1; m <= 32; m <<= 1) s += __shfl_xor(s, m);
    if (lane == 0) logit[k] = s + pb[k];
  }
  __syncthreads();
  if (lane == 0) {
    float mx = logit[0];
    for (int k = 1; k < 8; ++k) mx = fmaxf(mx, logit[k]);
    float z = 0.f, e[8];
    for (int k = 0; k < 8; ++k) { e[k] = __expf(logit[k] - mx); z += e[k]; }
    float inv = 1.f / z;
    for (int k = 0; k < 8; ++k) priors[(size_t)t * 8 + k] = e[k] * inv;
  }
}

// Shared GEMM mainloop: C[m,n] = A[m,:] . B[n,:]  (both row-major, K contiguous)
// 128x128 tile, 4 waves in 2x2, each wave 64x64 = 4x4 frags of 16x16, BK=64.
// Per K-step: { barrier; 8x global_load_lds(16B, source pre-swizzled);
// barrier (vmcnt0 drain); swizzled ds_read_b128 frags + 32 MFMA }.
// Swizzle: 16B-chunk kc of row r lives at LDS chunk slot kc^(r&7).
__device__ __forceinline__ void gemm_mainloop(
    const unsigned short* __restrict__ A, const unsigned short* __restrict__ B,
    int lda, int ldb, int m0, int n0, int ktiles,
    unsigned short* ldsA, unsigned short* ldsB, f32x4 acc[4][4]) {
  const int tid = threadIdx.x;
  const int lane = tid & 63;
  const int wave = tid >> 6;
  const int wm = wave & 1, wn = wave >> 1;
  const int lrow = lane & 15, lq = lane >> 4;

  for (int kt = 0; kt < ktiles; ++kt) {
    int k0 = kt * BK;
    __syncthreads();   // previous iter's LDS reads complete before DMA overwrites
    #pragma unroll
    for (int p = 0; p < 4; ++p) {
      int chunk = p * 256 + tid;          // 0..1023, 16B each = full 16KB tile
      int row = chunk >> 3, kc = chunk & 7;
      int kcs = kc ^ (row & 7);           // inverse-swizzle the global source
      __builtin_amdgcn_global_load_lds(
          (gas_u32p)(A + (size_t)(m0 + row) * lda + k0 + kcs * 8),
          (las_u32p)(ldsA + chunk * 8), 16, 0, 0);
      __builtin_amdgcn_global_load_lds(
          (gas_u32p)(B + (size_t)(n0 + row) * ldb + k0 + kcs * 8),
          (las_u32p)(ldsB + chunk * 8), 16, 0, 0);
    }
    __syncthreads();   // compiler emits vmcnt(0) drain: staged tiles visible
    #pragma unroll
    for (int s = 0; s < 2; ++s) {
      // swizzled read column: chunk (s*4+lq) of row (..+lrow) sits at slot ^(lrow&7)
      int cbyteoff = (((s * 4 + lq) ^ (lrow & 7)) * 8);
      bf16x8 af[4], bfr[4];
      #pragma unroll
      for (int f = 0; f < 4; ++f)
        af[f] = *(const bf16x8*)(ldsA + (wm * 64 + f * 16 + lrow) * BK + cbyteoff);
      #pragma unroll
      for (int f = 0; f < 4; ++f)
        bfr[f] = *(const bf16x8*)(ldsB + (wn * 64 + f * 16 + lrow) * BK + cbyteoff);
      #pragma unroll
      for (int fi = 0; fi < 4; ++fi)
        #pragma unroll
        for (int fj = 0; fj < 4; ++fj)
          acc[fi][fj] = __builtin_amdgcn_mfma_f32_16x16x32_bf16(af[fi], bfr[fj], acc[fi][fj], 0, 0, 0);
    }
  }
}

// Latent: [4096x1024] @ [4096x1024]^T, epilogue tanh(+bias), store bf16
// 1024 blocks: xcd-sliced (8 xcd x 4 col-tiles x 32 row-tiles)
__global__ __launch_bounds__(256, 4)
void k_latent(const unsigned short* __restrict__ ctxb, const unsigned short* __restrict__ lwb,
              const float* __restrict__ lb, unsigned short* __restrict__ latent) {
  __shared__ unsigned short lds[(BM + BN) * BK];
  f32x4 zero = {0.f, 0.f, 0.f, 0.f};
  f32x4 acc[4][4];
  #pragma unroll
  for (int i = 0; i < 4; ++i)
    #pragma unroll
    for (int j = 0; j < 4; ++j) acc[i][j] = zero;
  int l = blockIdx.x;
  int xcd = l & 7, idx = l >> 3;
  int ctl = idx & 3, by = idx >> 2;
  int m0 = by * BM, n0 = (xcd * 4 + ctl) * BN;
  gemm_mainloop(ctxb, lwb, 1024, 1024, m0, n0, 1024 / BK, lds, lds + BM * BK, acc);

  const int lane = threadIdx.x & 63, wave = threadIdx.x >> 6;
  const int wm = wave & 1, wn = wave >> 1, lrow = lane & 15, lq = lane >> 4;
  #pragma unroll
  for (int fi = 0; fi < 4; ++fi)
    #pragma unroll
    for (int fj = 0; fj < 4; ++fj) {
      int gcol = n0 + wn * 64 + fj * 16 + lrow;
      float bias = lb[gcol];
      #pragma unroll
      for (int r = 0; r < 4; ++r) {
        int grow = m0 + wm * 64 + fi * 16 + lq * 4 + r;
        float v = tanhf(acc[fi][fj][r] + bias);
        latent[(size_t)grow * 4096 + gcol] = f2bf(v);
      }
    }
}

// Decoder pass 1 over a row-chunk [m_base, m_base+rows): logits tile -> exp ->
// per-row sums -> atomicAdd Z.
// STORE=1: round exp to fp16, accumulate Z from the ROUNDED values, stage the
// 128x128 fp16 tile in LDS (16B-chunk XOR swizzle), write P (chunk-local rows)
// coalesced 16B/lane.
// grid: (rows/128)*80; xcd = l&7 owns col-tiles [xcd*10, xcd*10+10)
template<int STORE>
__global__ __launch_bounds__(256, 4)
void k_dec_pass1(const unsigned short* __restrict__ latb, const unsigned short* __restrict__ dwb,
                 const float* __restrict__ db, float* __restrict__ Z,
                 _Float16* __restrict__ P, int m_base) {
  __shared__ unsigned short lds[(BM + BN) * BK];
  int l = blockIdx.x;
  int xcd = l & 7, idx = l >> 3;
  int ctl = idx % 10, by = idx / 10;
  int n0 = (xcd * 10 + ctl) * BN, m0 = m_base + by * BM;
  if (n0 >= 10000) return;   // whole-block early exit (pure-pad tile), before any barrier

  f32x4 zero = {0.f, 0.f, 0.f, 0.f};
  f32x4 acc[4][4];
  #pragma unroll
  for (int i = 0; i < 4; ++i)
    #pragma unroll
    for (int j = 0; j < 4; ++j) acc[i][j] = zero;
  gemm_mainloop(latb, dwb, 512, 512, m0, n0, 512 / BK, lds, lds + BM * BK, acc);

  const int lane = threadIdx.x & 63, wave = threadIdx.x >> 6;
  const int wm = wave & 1, wn = wave >> 1, lrow = lane & 15, lq = lane >> 4;

  if (STORE) __syncthreads();       // mainloop LDS reads done in all waves before reuse
  _Float16* ldsP = (_Float16*)lds;  // 128x128 fp16 = 32 KB, exactly the LDS block

  float rowsum[4][4];
  #pragma unroll
  for (int fi = 0; fi < 4; ++fi)
    #pragma unroll
    for (int r = 0; r < 4; ++r) rowsum[fi][r] = 0.f;
  #pragma unroll
  for (int fj = 0; fj < 4; ++fj) {
    int gcol = n0 + wn * 64 + fj * 16 + lrow;
    bool valid = gcol < 10000;
    float bias = valid ? db[gcol] : 0.f;
    #pragma unroll
    for (int fi = 0; fi < 4; ++fi)
      #pragma unroll
      for (int r = 0; r < 4; ++r) {
        float e = __expf(acc[fi][fj][r] + bias);
        if (STORE) {
          _Float16 h = (_Float16)e;
          if (valid) rowsum[fi][r] += (float)h;
          int row_l = wm * 64 + fi * 16 + lq * 4 + r;
          int col_l = wn * 64 + fj * 16 + lrow;
          // 16B-chunk XOR swizzle: chunk (col>>3) of row r at slot ^(r&7)
          ldsP[row_l * 128 + (((col_l >> 3) ^ (row_l & 7)) << 3) + (col_l & 7)] = h;
        } else {
          if (valid) rowsum[fi][r] += e;
        }
      }
  }

  if (STORE) {
    __syncthreads();
    #pragma unroll
    for (int it = 0; it < 8; ++it) {
      int chunk = it * 256 + threadIdx.x;   // 0..2047 16B chunks = 32 KB
      int row_l = chunk >> 4, c8 = chunk & 15;
      int slot = c8 ^ (row_l & 7);
      uint4 v = *(const uint4*)((const char*)lds + row_l * 256 + slot * 16);
      // chunk-local row index: by*BM + row_l
      *(uint4*)(P + (size_t)(by * BM + row_l) * 10112 + n0 + c8 * 8) = v;
    }
  }

  #pragma unroll
  for (int fi = 0; fi < 4; ++fi)
    #pragma unroll
    for (int r = 0; r < 4; ++r) {
      float s = rowsum[fi][r];
      s += __shfl_xor(s, 1); s += __shfl_xor(s, 2);
      s += __shfl_xor(s, 4); s += __shfl_xor(s, 8);
      if (lrow == 0) atomicAdd(&Z[m0 + wm * 64 + fi * 16 + lq * 4 + r], s);
    }
}

// Combine (store path): out[t,c] = sum_k (prior/Z)[t,k] * P[tl*8+k][c].
// Pure streaming, 16B/lane fp16x8 loads, float4 stores. P chunk is
// L3-resident so the reads are Infinity-Cache hits (R6-measured ~4x faster).
// grid: (tokens_in_chunk, 5); block handles 256 col-chunks of 8.
__global__ __launch_bounds__(256)
void k_combine(const _Float16* __restrict__ P, const float* __restrict__ priors,
               const float* __restrict__ Z, float* __restrict__ out, int t_base) {
  int tl = blockIdx.x;              // chunk-local token
  int t  = t_base + tl;             // absolute token
  const _Float16* base = P + (size_t)tl * 8 * 10112;
  float w[8];
  #pragma unroll
  for (int k = 0; k < 8; ++k) w[k] = priors[t * 8 + k] / Z[t * 8 + k];
  int c8 = blockIdx.y * 256 + threadIdx.x;
  if (c8 < 1250) {
    int c = c8 * 8;
    float s[8] = {0.f, 0.f, 0.f, 0.f, 0.f, 0.f, 0.f, 0.f};
    #pragma unroll
    for (int k = 0; k < 8; ++k) {
      f16x8 v = *(const f16x8*)(base + (size_t)k * 10112 + c);
      #pragma unroll
      for (int j = 0; j < 8; ++j) s[j] += w[k] * (float)v[j];
    }
    float4 o0 = {s[0], s[1], s[2], s[3]};
    float4 o1 = {s[4], s[5], s[6], s[7]};
    *(float4*)(out + (size_t)t * 10000 + c) = o0;
    *(float4*)(out + (size_t)t * 10000 + c + 4) = o1;
  }
}

// Decoder pass 2 (fallback path, ws too small): recompute logits ->
// (prior/Z)*exp -> sum 8 k-rows -> stage 16x128 token tile -> float4 stores.
__global__ __launch_bounds__(256, 4)
void k_dec_pass2(const unsigned short* __restrict__ latb, const unsigned short* __restrict__ dwb,
                 const float* __restrict__ db, const float* __restrict__ priors,
                 const float* __restrict__ Z, float* __restrict__ out) {
  __shared__ unsigned short lds[(BM + BN) * BK];
  int l = blockIdx.x;
  int xcd = l & 7, idx = l >> 3;
  int ctl = idx % 10, by = idx / 10;
  int n0 = (xcd * 10 + ctl) * BN, m0 = by * BM;
  if (n0 >= 10000) return;

  f32x4 zero = {0.f, 0.f, 0.f, 0.f};
  f32x4 acc[4][4];
  #pragma unroll
  for (int i = 0; i < 4; ++i)
    #pragma unroll
    for (int j = 0; j < 4; ++j) acc[i][j] = zero;
  gemm_mainloop(latb, dwb, 512, 512, m0, n0, 512 / BK, lds, lds + BM * BK, acc);

  const int tid = threadIdx.x;
  const int lane = tid & 63, wave = tid >> 6;
  const int wm = wave & 1, wn = wave >> 1, lrow = lane & 15, lq = lane >> 4;

  __syncthreads();                    // mainloop LDS reads done in all waves
  float* ldsO = (float*)lds;          // reuse: 16 tokens x 128 cols = 8 KB

  #pragma unroll
  for (int fi = 0; fi < 4; ++fi) {
    int rbase = m0 + wm * 64 + fi * 16 + lq * 4;
    float w[4];
    #pragma unroll
    for (int r = 0; r < 4; ++r) w[r] = priors[rbase + r] / Z[rbase + r];
    #pragma unroll
    for (int fj = 0; fj < 4; ++fj) {
      int gcol = n0 + wn * 64 + fj * 16 + lrow;
      float bias = (gcol < 10000) ? db[gcol] : 0.f;
      float part = 0.f;
      #pragma unroll
      for (int r = 0; r < 4; ++r) part += w[r] * __expf(acc[fi][fj][r] + bias);
      // rows rbase..rbase+3 are k=0..3 of token (rbase>>3); k=4..7 at lane^16
      float tok = part + __shfl_xor(part, 16);
      if (!(lq & 1)) {
        int tl = wm * 8 + fi * 2 + (lq >> 1);     // local token 0..15
        int cl = wn * 64 + fj * 16 + lrow;        // local col 0..127
        ldsO[tl * 128 + cl] = tok;
      }
    }
  }
  __syncthreads();
  int tok0 = m0 >> 3;
  #pragma unroll
  for (int it = 0; it < 2; ++it) {
    int f = it * 256 + tid;           // 0..511 float4 slots
    int tl = f >> 5, c4 = f & 31;
    int col = n0 + c4 * 4;
    if (col < 10000)
      *(float4*)(out + (size_t)(tok0 + tl) * 10000 + col) = *(float4*)(ldsO + tl * 128 + c4 * 4);
  }
}

extern "C" void kernel_launch(void* const* d_in, const int* in_sizes, int n_in,
                              void* d_out, int out_size, void* d_ws, size_t ws_size,
                              hipStream_t stream) {
  const float* ctx = (const float*)d_in[0];  // [4096,1024]
  const float* pw  = (const float*)d_in[1];  // [8,1024]
  const float* pb  = (const float*)d_in[2];  // [8]
  const float* lw  = (const float*)d_in[3];  // [4096,1024]
  const float* lb  = (const float*)d_in[4];  // [4096]
  const float* dw  = (const float*)d_in[5];  // [10000,512]
  const float* db  = (const float*)d_in[6];  // [10000]
  float* out = (float*)d_out;

  char* ws = (char*)d_ws;
  unsigned short* ctxb = (unsigned short*)ws;                // 8,388,608 B
  unsigned short* lwb  = (unsigned short*)(ws + 8388608);    // 8,388,608 B
  unsigned short* dwb  = (unsigned short*)(ws + 16777216);   // 10112*512*2 = 10,354,688 B
  unsigned short* latb = (unsigned short*)(ws + 27131904);   // 32768*512*2 = 33,554,432 B
  float* priors        = (float*)(ws + 60686336);            // 131,072 B
  float* Z             = (float*)(ws + 60817408);            // 131,072 B
  _Float16* Pex        = (_Float16*)(ws + 60948480);         // chunk buffer, sized from ws
  const size_t WS_BASE = 60948480ull;

  // Chunk sizing: target 8192 rows -> P chunk = 8192*10112*2 = 165.7 MB.
  // Combine reads stay L3-resident (working set ~226 MB < 256 MB), while
  // pass1 grid = 5120 blocks = 5.0 resident-rounds (vs R6's 2.5 at 4096 rows,
  // whose tail+ramp cost 1.8x per-row). R6 measured: combine-from-L3 ~4x
  // faster than HBM; L3 does NOT absorb the P writes (accepted cost).
  size_t avail = ws_size > WS_BASE ? ws_size - WS_BASE : 0;
  long long mrows_ll = (long long)(avail / (10112ull * 2ull)) & ~127ll;
  if (mrows_ll > 8192) mrows_ll = 8192;
  int mrows = (int)mrows_ll;
  int nch = mrows > 0 ? (32768 + mrows - 1) / mrows : 1000;
  const bool store_path = (nch <= 16);

  k_cvt_bf16<<<4096, 256, 0, stream>>>((const float4*)ctx, (ushort4*)ctxb, 1048576);
  k_cvt_bf16<<<4096, 256, 0, stream>>>((const float4*)lw,  (ushort4*)lwb,  1048576);
  k_cvt_bf16<<<5000, 256, 0, stream>>>((const float4*)dw,  (ushort4*)dwb,  1280000);
  hipMemsetAsync(dwb + (size_t)10000 * 512, 0, (size_t)112 * 512 * 2, stream);  // zero pad rows
  hipMemsetAsync(Z, 0, 32768 * 4, stream);

  k_priors<<<4096, 64, 0, stream>>>(ctx, pw, pb, priors);
  k_latent<<<1024, 256, 0, stream>>>(ctxb, lwb, lb, latb);
  if (store_path) {
    for (int ms = 0; ms < 32768; ms += mrows) {
      int rows = 32768 - ms < mrows ? 32768 - ms : mrows;   // multiple of 128
      k_dec_pass1<1><<<(rows / 128) * 80, 256, 0, stream>>>(latb, dwb, db, Z, Pex, ms);
      k_combine<<<dim3(rows / 8, 5), 256, 0, stream>>>(Pex, priors, Z, out, ms / 8);
    }
  } else {
    k_dec_pass1<0><<<20480, 256, 0, stream>>>(latb, dwb, db, Z, nullptr, 0);
    k_dec_pass2<<<20480, 256, 0, stream>>>(latb, dwb, db, priors, Z, out);
  }
}